// Round 8
// baseline (261.779 us; speedup 1.0000x reference)
//
#include <hip/hip_runtime.h>
#include <hip/hip_bf16.h>
#include <stdint.h>

#define D 768
#define HEADS 12
#define DHEAD 64
#define DFF 3072
#define TOTAL 4608
#define NSEG 8

typedef __bf16 bf16;
typedef __bf16 bf16x8 __attribute__((ext_vector_type(8)));
typedef __bf16 bf16x4 __attribute__((ext_vector_type(4)));
typedef float f32x4 __attribute__((ext_vector_type(4)));

// async global->LDS, 16B per lane; lptr must be wave-uniform (lane lands at +lane*16)
__device__ __forceinline__ void gld_lds16(const void* g, void* l) {
  __builtin_amdgcn_global_load_lds(
      (const __attribute__((address_space(1))) void*)g,
      (__attribute__((address_space(3))) void*)(uintptr_t)l, 16, 0, 0);
}

// ---------------------------------------------------------------- convert
// All four weight dst regions are contiguous in ws -> one kernel.
__global__ __launch_bounds__(256) void cvt_all_kernel(
    const float* __restrict__ a, const float* __restrict__ b,
    const float* __restrict__ c, const float* __restrict__ d,
    bf16* __restrict__ out, int nA, int nAB, int nABC, int nTot) {
  int i = blockIdx.x * blockDim.x + threadIdx.x;
  if (i >= nTot) return;
  const float* src;
  int j;
  if (i < nA) { src = a; j = i; }
  else if (i < nAB) { src = b; j = i - nA; }
  else if (i < nABC) { src = c; j = i - nAB; }
  else { src = d; j = i - nABC; }
  float4 v = ((const float4*)src)[j];
  bf16x4 o;
  o[0] = (bf16)v.x; o[1] = (bf16)v.y; o[2] = (bf16)v.z; o[3] = (bf16)v.w;
  ((bf16x4*)out)[i] = o;
}

// ---------------------------------------------------------------- layernorm
__global__ __launch_bounds__(256) void ln_kernel(
    const float* __restrict__ x, const float* __restrict__ w,
    const float* __restrict__ b, bf16* __restrict__ out) {
  __shared__ float red[8];
  int row = blockIdx.x;
  const float* xr = x + (size_t)row * D;
  int t = threadIdx.x;
  float v[3];
  float s = 0.f, s2 = 0.f;
#pragma unroll
  for (int j = 0; j < 3; j++) {
    v[j] = xr[t + 256 * j];
    s += v[j]; s2 += v[j] * v[j];
  }
#pragma unroll
  for (int m = 1; m <= 32; m <<= 1) {
    s += __shfl_xor(s, m);
    s2 += __shfl_xor(s2, m);
  }
  int wave = t >> 6, lane = t & 63;
  if (lane == 0) { red[wave] = s; red[4 + wave] = s2; }
  __syncthreads();
  s = red[0] + red[1] + red[2] + red[3];
  s2 = red[4] + red[5] + red[6] + red[7];
  float mu = s * (1.f / 768.f);
  float var = s2 * (1.f / 768.f) - mu * mu;
  float rstd = rsqrtf(var + 1e-6f);
#pragma unroll
  for (int j = 0; j < 3; j++) {
    int c = t + 256 * j;
    out[(size_t)row * D + c] = (bf16)((v[j] - mu) * rstd * w[c] + b[c]);
  }
}

__device__ __forceinline__ float fast_gelu(float v) {
  // tanh-form gelu; tanh via exp2 + rcp. |err| ~3e-4 vs exact erf form.
  float u = v * (0.7978845608f + 0.0356774081f * v * v);
  float e = exp2f(2.8853900818f * u);              // exp(2u)
  float th = 1.f - 2.f * __builtin_amdgcn_rcpf(1.f + e);
  return 0.5f * v * (1.f + th);
}

// ---------------------------------------------------------------- GEMM
// C[M][N] = A[M][K] @ W[N][K]^T (+ epilogue). 128xTN tile, BK=64,
// double-buffered single-barrier K-loop with gld_lds prefetch.
// LDS column-group XOR swizzle (staging-applied, read-undone) -> 0 conflicts.
// XCD-grouped 1D grid: block g -> xcd g&7; y-slabs with y%8==xcd stay on one
// XCD so the A-slab lives in that XCD's L2 across the x-sweep.
// MODE 0: out_bf16 = acc + bias
// MODE 1: out_f32  = res + gamma * (acc + bias)
// MODE 2: out_bf16 = fast_gelu(acc + bias)
template <int MODE, int TN, int BK, int GX, int GY>
__global__ __launch_bounds__(256) void gemm_kernel(
    const bf16* __restrict__ A, const bf16* __restrict__ W,
    const float* __restrict__ bias, const float* __restrict__ res,
    const float* __restrict__ gamma, bf16* __restrict__ outb,
    float* __restrict__ outf, int N, int K) {
  constexpr int NJ = TN / 32;   // B frags per wave per k-step
  constexpr int KH = BK / 32;   // MFMA k-steps per iter
  constexpr int CG = BK / 8;    // 8-elem column groups per row
  constexpr int SH = (BK == 32) ? 1 : 0;  // swizzle shift: s(r)=(r>>SH)&(CG-1)
  constexpr int LPR = BK / 8;   // staging lanes per row
  constexpr int RS = 64 / LPR;  // staging rows per instruction
  constexpr int RB = TN / 4;    // B rows staged per wave
  __shared__ __align__(16) bf16 As[2][128 * BK];
  __shared__ __align__(16) bf16 Bs[2][TN * BK];

  // XCD-grouped decode of the 1D grid (padded so 8 | y-count)
  const int g = blockIdx.x;
  const int xc = g & 7, q = g >> 3;
  const int bx = q % GX, by = xc + 8 * (q / GX);
  if (by >= GY) return;
  const int m0 = by * 128, n0 = bx * TN;

  const int t = threadIdx.x, wave = t >> 6, lane = t & 63;
  const int quad = lane >> 4, l16 = lane & 15;
  const int wm = (wave & 1) * 64, wn = (wave >> 1) * (TN / 2);

  // staging: A wave rows [w*32, w*32+32), B wave rows [w*RB, w*RB+RB)
  const int ar = lane / LPR, ac = lane % LPR;
  const int acg = ac ^ (((wave * 32 + ar) >> SH) & (CG - 1));
  const int bcg = ac ^ (((wave * RB + ar) >> SH) & (CG - 1));
  const bf16* gA = A + (size_t)(m0 + wave * 32 + ar) * K + acg * 8;
  const bf16* gB = W + (size_t)(n0 + wave * RB + ar) * K + bcg * 8;

  auto stage = [&](int buf) {
#pragma unroll
    for (int n = 0; n < 32 / RS; n++)
      gld_lds16(gA + (size_t)n * RS * K, &As[buf][(wave * 32 + n * RS) * BK]);
#pragma unroll
    for (int n = 0; n < RB / RS; n++)
      gld_lds16(gB + (size_t)n * RS * K, &Bs[buf][(wave * RB + n * RS) * BK]);
    gA += BK; gB += BK;
  };

  stage(0);  // prologue

  f32x4 acc[4][NJ] = {};
  int cur = 0;
  for (int k0 = 0; k0 < K; k0 += BK) {
    __syncthreads();  // drains vmcnt: buf[cur] ready; lgkmcnt: buf[cur^1] reads done
    if (k0 + BK < K) stage(cur ^ 1);
    const bf16* as = As[cur];
    const bf16* bs = Bs[cur];
    bf16x8 af[KH][4], bg[KH][NJ];
#pragma unroll
    for (int kh = 0; kh < KH; kh++) {
#pragma unroll
      for (int i = 0; i < 4; i++) {
        int R = wm + i * 16 + l16;
        af[kh][i] = *(const bf16x8*)&as[R * BK + 8 * ((kh * 4 + quad) ^ ((R >> SH) & (CG - 1)))];
      }
#pragma unroll
      for (int j = 0; j < NJ; j++) {
        int R = wn + j * 16 + l16;
        bg[kh][j] = *(const bf16x8*)&bs[R * BK + 8 * ((kh * 4 + quad) ^ ((R >> SH) & (CG - 1)))];
      }
    }
#pragma unroll
    for (int kh = 0; kh < KH; kh++)
#pragma unroll
      for (int i = 0; i < 4; i++)
#pragma unroll
        for (int j = 0; j < NJ; j++)
          acc[i][j] = __builtin_amdgcn_mfma_f32_16x16x32_bf16(af[kh][i], bg[kh][j], acc[i][j], 0, 0, 0);
    cur ^= 1;
  }

#pragma unroll
  for (int i = 0; i < 4; i++)
#pragma unroll
    for (int j = 0; j < NJ; j++)
#pragma unroll
      for (int r = 0; r < 4; r++) {
        int row = m0 + wm + i * 16 + quad * 4 + r;
        int col = n0 + wn + j * 16 + l16;
        float v = acc[i][j][r] + bias[col];
        if (MODE == 0) {
          outb[(size_t)row * N + col] = (bf16)v;
        } else if (MODE == 1) {
          outf[(size_t)row * N + col] = res[(size_t)row * N + col] + gamma[col] * v;
        } else {
          outb[(size_t)row * N + col] = (bf16)fast_gelu(v);
        }
      }
}

// ---------------------------------------------------------------- attention
// Flash-style per (64-query tile, head), max-free softmax, S^T=K.Q^T layout
// trick (P exits in PV's B-frag layout; V^T staged in permuted key order).
// DEPTH-2 SOFTWARE PIPELINE: double-buffered Ks/VTs, two register sets (A/B),
// one barrier per tile; global loads get a full compute phase of cover and
// LDS writes of tile t+1 overlap compute of tile t.
__global__ __launch_bounds__(256) void attn_kernel(
    const bf16* __restrict__ qkv, const int* __restrict__ cu,
    bf16* __restrict__ attn) {
  __shared__ __align__(16) bf16 Ks[2][64][72];
  __shared__ __align__(16) bf16 VTs[2][64][64];  // [d][kB ^ ((d&7)*8)]

  const int qt = blockIdx.y, h = blockIdx.x;  // h fastest: heavy qt spread first
  const int tok0 = qt * 64;
  int b = 0;
  while (cu[b + 1] <= tok0) b++;
  const int s0 = cu[b], S = cu[b + 1] - s0;
  const int n = S >> 6;  // tiles

  const int t = threadIdx.x, wave = t >> 6, lane = t & 63;
  const int quad = lane >> 4, l16 = lane & 15;

  // Q B-frags from global (q = tok0 + wave*16 + l16)
  const size_t qrow = (size_t)(tok0 + wave * 16 + l16) * (3 * D) + h * 64;
  const bf16x8 bq0 = *(const bf16x8*)&qkv[qrow + quad * 8];
  const bf16x8 bq1 = *(const bf16x8*)&qkv[qrow + 32 + quad * 8];

  // K staging map: row = t>>2, cols [sc0, sc0+16)
  const int srow = t >> 2, sc0 = (t & 3) * 16;
  const size_t kbase = (size_t)(s0 + srow) * (3 * D) + h * 64 + sc0 + D;
  // V staging map: 4x4 block at rows vr0..+3, cols vd0..+3
  const int vr0 = (t & 15) * 4, vd0 = (t >> 4) * 4;
  const size_t vbase = (size_t)(s0 + vr0) * (3 * D) + h * 64 + vd0 + 2 * D;
  // permuted key label for vr0 (aligned-4 group stays contiguous):
  const int kB0 = ((vr0 >> 5) << 5) | (((vr0 >> 2) & 3) << 3) | (((vr0 >> 4) & 1) << 2);

  f32x4 Oacc[4] = {};
  float li = 0.f;
  const float SC = 0.125f * 1.44269504089f;  // DH^-0.5 * log2(e)

  bf16x8 kA0, kA1, kB0r, kB1r;
  bf16x4 vA[4], vB[4];

  auto loadT = [&](int tile, bf16x8& k0, bf16x8& k1, bf16x4* vp) {
    const size_t ko = kbase + (size_t)tile * 64 * (3 * D);
    const size_t vo = vbase + (size_t)tile * 64 * (3 * D);
    k0 = *(const bf16x8*)&qkv[ko];
    k1 = *(const bf16x8*)&qkv[ko + 8];
#pragma unroll
    for (int i = 0; i < 4; i++)
      vp[i] = *(const bf16x4*)&qkv[vo + (size_t)i * (3 * D)];
  };
  auto writeT = [&](int buf, const bf16x8& k0, const bf16x8& k1, const bf16x4* vp) {
    *(bf16x8*)&Ks[buf][srow][sc0] = k0;
    *(bf16x8*)&Ks[buf][srow][sc0 + 8] = k1;
#pragma unroll
    for (int j = 0; j < 4; j++) {
      int d = vd0 + j;
      bf16x4 w;
      w[0] = vp[0][j]; w[1] = vp[1][j]; w[2] = vp[2][j]; w[3] = vp[3][j];
      *(bf16x4*)&VTs[buf][d][kB0 ^ ((d & 7) * 8)] = w;
    }
  };
  auto computeT = [&](int buf) {
    // S^T = K Q^T : C rows = keys, cols = q
    f32x4 sac[4];
#pragma unroll
    for (int nt = 0; nt < 4; nt++) {
      bf16x8 ak0 = *(const bf16x8*)&Ks[buf][nt * 16 + l16][quad * 8];
      bf16x8 ak1 = *(const bf16x8*)&Ks[buf][nt * 16 + l16][32 + quad * 8];
      f32x4 z = {};
      z = __builtin_amdgcn_mfma_f32_16x16x32_bf16(ak0, bq0, z, 0, 0, 0);
      sac[nt] = __builtin_amdgcn_mfma_f32_16x16x32_bf16(ak1, bq1, z, 0, 0, 0);
    }
    // exp (max-free) + pack straight into PV B-frags
    bf16x8 pv0, pv1;
    float ls = 0.f;
#pragma unroll
    for (int r = 0; r < 4; r++) {
      float e0 = exp2f(sac[0][r] * SC);
      float e1 = exp2f(sac[1][r] * SC);
      float e2 = exp2f(sac[2][r] * SC);
      float e3 = exp2f(sac[3][r] * SC);
      ls += (e0 + e1) + (e2 + e3);
      pv0[r] = (bf16)e0; pv0[4 + r] = (bf16)e1;
      pv1[r] = (bf16)e2; pv1[4 + r] = (bf16)e3;
    }
    li += ls;
    // O^T += V^T P^T
    const int vsw = (l16 & 7) * 8;
#pragma unroll
    for (int dt = 0; dt < 4; dt++) {
      bf16x8 av0 = *(const bf16x8*)&VTs[buf][dt * 16 + l16][(quad * 8) ^ vsw];
      bf16x8 av1 = *(const bf16x8*)&VTs[buf][dt * 16 + l16][(32 + quad * 8) ^ vsw];
      Oacc[dt] = __builtin_amdgcn_mfma_f32_16x16x32_bf16(av0, pv0, Oacc[dt], 0, 0, 0);
      Oacc[dt] = __builtin_amdgcn_mfma_f32_16x16x32_bf16(av1, pv1, Oacc[dt], 0, 0, 0);
    }
  };

  // prologue: tile0 -> set A -> LDS buf0; tile1 -> set B (in flight)
  loadT(0, kA0, kA1, vA);
  if (n > 1) loadT(1, kB0r, kB1r, vB);
  writeT(0, kA0, kA1, vA);

  for (int tt = 0; tt < n; tt += 2) {
    __syncthreads();  // buf0 writes visible; prior reads of buf1 done
    if (tt + 1 < n) writeT(1, kB0r, kB1r, vB);
    if (tt + 2 < n) loadT(tt + 2, kA0, kA1, vA);
    computeT(0);
    if (tt + 1 >= n) break;
    __syncthreads();  // buf1 writes visible; prior reads of buf0 done
    if (tt + 2 < n) writeT(0, kA0, kA1, vA);
    if (tt + 3 < n) loadT(tt + 3, kB0r, kB1r, vB);
    computeT(1);
  }

  // reduce li across quads (q = l16 fixed per lane across all its values)
  li += __shfl_xor(li, 16);
  li += __shfl_xor(li, 32);
  const float inv = 1.f / li;

  // epilogue: transpose O^T via LDS (reuse Ks[0]) for coalesced stores
  __syncthreads();  // all waves done reading Ks/VTs
  bf16(*Osh)[72] = (bf16(*)[72])Ks[0];
  const int orow = wave * 16 + l16;
#pragma unroll
  for (int dt = 0; dt < 4; dt++) {
    int dg = dt * 16 + quad * 4;
    bf16x4 w;
#pragma unroll
    for (int r = 0; r < 4; r++) w[r] = (bf16)(Oacc[dt][r] * inv);
    *(bf16x4*)&Osh[orow][dg ^ ((l16 & 7) * 8)] = w;  // wave-private row
  }
  // read back own row (within-wave: lgkm ordering only, no barrier)
  const int osw = (l16 & 7) * 8;
  bf16x8 o0 = *(const bf16x8*)&Osh[orow][(quad * 16) ^ osw];
  bf16x8 o1 = *(const bf16x8*)&Osh[orow][(quad * 16 + 8) ^ osw];
  const size_t obase = (size_t)(tok0 + orow) * D + h * 64 + quad * 16;
  *(bf16x8*)&attn[obase] = o0;
  *(bf16x8*)&attn[obase + 8] = o1;
}

// ---------------------------------------------------------------- launch
extern "C" void kernel_launch(void* const* d_in, const int* in_sizes, int n_in,
                              void* d_out, int out_size, void* d_ws,
                              size_t ws_size, hipStream_t stream) {
  const float* x       = (const float*)d_in[0];
  const float* norm1_w = (const float*)d_in[1];
  const float* norm1_b = (const float*)d_in[2];
  const float* qkv_w   = (const float*)d_in[3];
  const float* qkv_b   = (const float*)d_in[4];
  const float* proj_w  = (const float*)d_in[5];
  const float* proj_b  = (const float*)d_in[6];
  const float* ls1     = (const float*)d_in[7];
  const float* norm2_w = (const float*)d_in[8];
  const float* norm2_b = (const float*)d_in[9];
  const float* fc1_w   = (const float*)d_in[10];
  const float* fc1_b   = (const float*)d_in[11];
  const float* fc2_w   = (const float*)d_in[12];
  const float* fc2_b   = (const float*)d_in[13];
  const float* ls2     = (const float*)d_in[14];
  const int*   cu      = (const int*)d_in[15];
  float* out = (float*)d_out;

  char* ws = (char*)d_ws;
  size_t off = 0;
  auto alloc = [&](size_t bytes) {
    void* p = ws + off;
    off += (bytes + 255) & ~(size_t)255;
    return p;
  };
  bf16* w_qkv  = (bf16*)alloc((size_t)3 * D * D * 2);
  bf16* w_proj = (bf16*)alloc((size_t)D * D * 2);
  bf16* w_fc1  = (bf16*)alloc((size_t)DFF * D * 2);
  bf16* w_fc2  = (bf16*)alloc((size_t)D * DFF * 2);
  bf16* xn     = (bf16*)alloc((size_t)TOTAL * D * 2);      // reused as xn2
  bf16* qkv    = (bf16*)alloc((size_t)TOTAL * 3 * D * 2);  // h aliases qkv+attnb
  bf16* attnb  = (bf16*)alloc((size_t)TOTAL * D * 2);
  float* x1    = (float*)alloc((size_t)TOTAL * D * 4);
  bf16* hbuf   = qkv;  // [TOTAL][DFF] overlaps dead qkv(3D)+attnb(D) exactly

  // one conversion kernel: dst regions are exactly contiguous from w_qkv
  {
    int nA   = 3 * D * D / 4;
    int nAB  = nA + D * D / 4;
    int nABC = nAB + DFF * D / 4;
    int nTot = nABC + D * DFF / 4;
    cvt_all_kernel<<<(nTot + 255) / 256, 256, 0, stream>>>(
        qkv_w, proj_w, fc1_w, fc2_w, w_qkv, nA, nAB, nABC, nTot);
  }

  ln_kernel<<<TOTAL, 256, 0, stream>>>(x, norm1_w, norm1_b, xn);

  constexpr int GY = TOTAL / 128;        // 36 M-tiles
  constexpr int GYP = ((GY + 7) / 8) * 8;  // padded to 40

  // QKV: N=2304, GX=18
  gemm_kernel<0, 128, 64, 18, GY><<<18 * GYP, 256, 0, stream>>>(
      xn, w_qkv, qkv_b, nullptr, nullptr, qkv, nullptr, 3 * D, D);

  dim3 ga(HEADS, TOTAL / 64);  // h fastest: heavy q-tiles spread across CUs
  attn_kernel<<<ga, 256, 0, stream>>>(qkv, cu, attnb);

  // proj: N=768, TN=64, GX=12
  gemm_kernel<1, 64, 64, 12, GY><<<12 * GYP, 256, 0, stream>>>(
      attnb, w_proj, proj_b, x, ls1, nullptr, x1, D, D);

  ln_kernel<<<TOTAL, 256, 0, stream>>>(x1, norm2_w, norm2_b, xn);

  // FC1: N=3072, GX=24
  gemm_kernel<2, 128, 64, 24, GY><<<24 * GYP, 256, 0, stream>>>(
      xn, w_fc1, fc1_b, nullptr, nullptr, hbuf, nullptr, DFF, D);

  // FC2: N=768, TN=64, K=3072, GX=12
  gemm_kernel<1, 64, 64, 12, GY><<<12 * GYP, 256, 0, stream>>>(
      hbuf, w_fc2, fc2_b, x1, ls2, nullptr, out, D, DFF);
}

// Round 9
// 260.119 us; speedup vs baseline: 1.0064x; 1.0064x over previous
//
#include <hip/hip_runtime.h>
#include <hip/hip_bf16.h>
#include <stdint.h>

#define D 768
#define HEADS 12
#define DHEAD 64
#define DFF 3072
#define TOTAL 4608
#define NSEG 8

typedef __bf16 bf16;
typedef __bf16 bf16x8 __attribute__((ext_vector_type(8)));
typedef __bf16 bf16x4 __attribute__((ext_vector_type(4)));
typedef float f32x4 __attribute__((ext_vector_type(4)));

// async global->LDS, 16B per lane; lptr must be wave-uniform (lane lands at +lane*16)
__device__ __forceinline__ void gld_lds16(const void* g, void* l) {
  __builtin_amdgcn_global_load_lds(
      (const __attribute__((address_space(1))) void*)g,
      (__attribute__((address_space(3))) void*)(uintptr_t)l, 16, 0, 0);
}

// barrier that does NOT drain vmcnt: cross-wave LDS visibility only needs
// each wave's own lgkm ops complete (ds_writes published, ds_reads of the
// to-be-overwritten buffer delivered). Global prefetch loads stay in flight.
__device__ __forceinline__ void lds_barrier() {
  asm volatile("s_waitcnt lgkmcnt(0)\n\ts_barrier" ::: "memory");
}

// ---------------------------------------------------------------- convert
// All four weight dst regions are contiguous in ws -> one kernel.
__global__ __launch_bounds__(256) void cvt_all_kernel(
    const float* __restrict__ a, const float* __restrict__ b,
    const float* __restrict__ c, const float* __restrict__ d,
    bf16* __restrict__ out, int nA, int nAB, int nABC, int nTot) {
  int i = blockIdx.x * blockDim.x + threadIdx.x;
  if (i >= nTot) return;
  const float* src;
  int j;
  if (i < nA) { src = a; j = i; }
  else if (i < nAB) { src = b; j = i - nA; }
  else if (i < nABC) { src = c; j = i - nAB; }
  else { src = d; j = i - nABC; }
  float4 v = ((const float4*)src)[j];
  bf16x4 o;
  o[0] = (bf16)v.x; o[1] = (bf16)v.y; o[2] = (bf16)v.z; o[3] = (bf16)v.w;
  ((bf16x4*)out)[i] = o;
}

// ---------------------------------------------------------------- layernorm
__global__ __launch_bounds__(256) void ln_kernel(
    const float* __restrict__ x, const float* __restrict__ w,
    const float* __restrict__ b, bf16* __restrict__ out) {
  __shared__ float red[8];
  int row = blockIdx.x;
  const float* xr = x + (size_t)row * D;
  int t = threadIdx.x;
  float v[3];
  float s = 0.f, s2 = 0.f;
#pragma unroll
  for (int j = 0; j < 3; j++) {
    v[j] = xr[t + 256 * j];
    s += v[j]; s2 += v[j] * v[j];
  }
#pragma unroll
  for (int m = 1; m <= 32; m <<= 1) {
    s += __shfl_xor(s, m);
    s2 += __shfl_xor(s2, m);
  }
  int wave = t >> 6, lane = t & 63;
  if (lane == 0) { red[wave] = s; red[4 + wave] = s2; }
  __syncthreads();
  s = red[0] + red[1] + red[2] + red[3];
  s2 = red[4] + red[5] + red[6] + red[7];
  float mu = s * (1.f / 768.f);
  float var = s2 * (1.f / 768.f) - mu * mu;
  float rstd = rsqrtf(var + 1e-6f);
#pragma unroll
  for (int j = 0; j < 3; j++) {
    int c = t + 256 * j;
    out[(size_t)row * D + c] = (bf16)((v[j] - mu) * rstd * w[c] + b[c]);
  }
}

__device__ __forceinline__ float fast_gelu(float v) {
  // tanh-form gelu; tanh via exp2 + rcp. |err| ~3e-4 vs exact erf form.
  float u = v * (0.7978845608f + 0.0356774081f * v * v);
  float e = exp2f(2.8853900818f * u);              // exp(2u)
  float th = 1.f - 2.f * __builtin_amdgcn_rcpf(1.f + e);
  return 0.5f * v * (1.f + th);
}

// ---------------------------------------------------------------- GEMM
// C[M][N] = A[M][K] @ W[N][K]^T (+ epilogue). 128xTN tile, BK=64,
// double-buffered single-barrier K-loop with gld_lds prefetch.
// LDS column-group XOR swizzle (staging-applied, read-undone) -> 0 conflicts.
// XCD-grouped 1D grid: block g -> xcd g&7; y-slabs with y%8==xcd stay on one
// XCD so the A-slab lives in that XCD's L2 across the x-sweep.
// MODE 0: out_bf16 = acc + bias
// MODE 1: out_f32  = res + gamma * (acc + bias)
// MODE 2: out_bf16 = fast_gelu(acc + bias)
template <int MODE, int TN, int BK, int GX, int GY>
__global__ __launch_bounds__(256) void gemm_kernel(
    const bf16* __restrict__ A, const bf16* __restrict__ W,
    const float* __restrict__ bias, const float* __restrict__ res,
    const float* __restrict__ gamma, bf16* __restrict__ outb,
    float* __restrict__ outf, int N, int K) {
  constexpr int NJ = TN / 32;   // B frags per wave per k-step
  constexpr int KH = BK / 32;   // MFMA k-steps per iter
  constexpr int CG = BK / 8;    // 8-elem column groups per row
  constexpr int SH = (BK == 32) ? 1 : 0;  // swizzle shift: s(r)=(r>>SH)&(CG-1)
  constexpr int LPR = BK / 8;   // staging lanes per row
  constexpr int RS = 64 / LPR;  // staging rows per instruction
  constexpr int RB = TN / 4;    // B rows staged per wave
  __shared__ __align__(16) bf16 As[2][128 * BK];
  __shared__ __align__(16) bf16 Bs[2][TN * BK];

  // XCD-grouped decode of the 1D grid (padded so 8 | y-count)
  const int g = blockIdx.x;
  const int xc = g & 7, q = g >> 3;
  const int bx = q % GX, by = xc + 8 * (q / GX);
  if (by >= GY) return;
  const int m0 = by * 128, n0 = bx * TN;

  const int t = threadIdx.x, wave = t >> 6, lane = t & 63;
  const int quad = lane >> 4, l16 = lane & 15;
  const int wm = (wave & 1) * 64, wn = (wave >> 1) * (TN / 2);

  // staging: A wave rows [w*32, w*32+32), B wave rows [w*RB, w*RB+RB)
  const int ar = lane / LPR, ac = lane % LPR;
  const int acg = ac ^ (((wave * 32 + ar) >> SH) & (CG - 1));
  const int bcg = ac ^ (((wave * RB + ar) >> SH) & (CG - 1));
  const bf16* gA = A + (size_t)(m0 + wave * 32 + ar) * K + acg * 8;
  const bf16* gB = W + (size_t)(n0 + wave * RB + ar) * K + bcg * 8;

  auto stage = [&](int buf) {
#pragma unroll
    for (int n = 0; n < 32 / RS; n++)
      gld_lds16(gA + (size_t)n * RS * K, &As[buf][(wave * 32 + n * RS) * BK]);
#pragma unroll
    for (int n = 0; n < RB / RS; n++)
      gld_lds16(gB + (size_t)n * RS * K, &Bs[buf][(wave * RB + n * RS) * BK]);
    gA += BK; gB += BK;
  };

  stage(0);  // prologue

  f32x4 acc[4][NJ] = {};
  int cur = 0;
  for (int k0 = 0; k0 < K; k0 += BK) {
    __syncthreads();  // drains vmcnt: buf[cur] ready; lgkmcnt: buf[cur^1] reads done
    if (k0 + BK < K) stage(cur ^ 1);
    const bf16* as = As[cur];
    const bf16* bs = Bs[cur];
    bf16x8 af[KH][4], bg[KH][NJ];
#pragma unroll
    for (int kh = 0; kh < KH; kh++) {
#pragma unroll
      for (int i = 0; i < 4; i++) {
        int R = wm + i * 16 + l16;
        af[kh][i] = *(const bf16x8*)&as[R * BK + 8 * ((kh * 4 + quad) ^ ((R >> SH) & (CG - 1)))];
      }
#pragma unroll
      for (int j = 0; j < NJ; j++) {
        int R = wn + j * 16 + l16;
        bg[kh][j] = *(const bf16x8*)&bs[R * BK + 8 * ((kh * 4 + quad) ^ ((R >> SH) & (CG - 1)))];
      }
    }
#pragma unroll
    for (int kh = 0; kh < KH; kh++)
#pragma unroll
      for (int i = 0; i < 4; i++)
#pragma unroll
        for (int j = 0; j < NJ; j++)
          acc[i][j] = __builtin_amdgcn_mfma_f32_16x16x32_bf16(af[kh][i], bg[kh][j], acc[i][j], 0, 0, 0);
    cur ^= 1;
  }

#pragma unroll
  for (int i = 0; i < 4; i++)
#pragma unroll
    for (int j = 0; j < NJ; j++)
#pragma unroll
      for (int r = 0; r < 4; r++) {
        int row = m0 + wm + i * 16 + quad * 4 + r;
        int col = n0 + wn + j * 16 + l16;
        float v = acc[i][j][r] + bias[col];
        if (MODE == 0) {
          outb[(size_t)row * N + col] = (bf16)v;
        } else if (MODE == 1) {
          outf[(size_t)row * N + col] = res[(size_t)row * N + col] + gamma[col] * v;
        } else {
          outb[(size_t)row * N + col] = (bf16)fast_gelu(v);
        }
      }
}

// ---------------------------------------------------------------- attention
// Flash-style per (64-query tile, head), max-free softmax, S^T=K.Q^T layout
// trick (P exits in PV's B-frag layout; V^T staged in permuted key order).
// Depth-2 pipeline + lds_barrier(): barriers wait lgkmcnt only, so the
// global K/V prefetch (issued 2 tiles ahead) stays in flight across them.
__global__ __launch_bounds__(256) void attn_kernel(
    const bf16* __restrict__ qkv, const int* __restrict__ cu,
    bf16* __restrict__ attn) {
  __shared__ __align__(16) bf16 Ks[2][64][72];
  __shared__ __align__(16) bf16 VTs[2][64][64];  // [d][kB ^ ((d&7)*8)]

  const int qt = blockIdx.y, h = blockIdx.x;  // h fastest: heavy qt spread first
  const int tok0 = qt * 64;
  int b = 0;
  while (cu[b + 1] <= tok0) b++;
  const int s0 = cu[b], S = cu[b + 1] - s0;
  const int n = S >> 6;  // tiles

  const int t = threadIdx.x, wave = t >> 6, lane = t & 63;
  const int quad = lane >> 4, l16 = lane & 15;

  // Q B-frags from global (q = tok0 + wave*16 + l16)
  const size_t qrow = (size_t)(tok0 + wave * 16 + l16) * (3 * D) + h * 64;
  const bf16x8 bq0 = *(const bf16x8*)&qkv[qrow + quad * 8];
  const bf16x8 bq1 = *(const bf16x8*)&qkv[qrow + 32 + quad * 8];

  // K staging map: row = t>>2, cols [sc0, sc0+16)
  const int srow = t >> 2, sc0 = (t & 3) * 16;
  const size_t kbase = (size_t)(s0 + srow) * (3 * D) + h * 64 + sc0 + D;
  // V staging map: 4x4 block at rows vr0..+3, cols vd0..+3
  const int vr0 = (t & 15) * 4, vd0 = (t >> 4) * 4;
  const size_t vbase = (size_t)(s0 + vr0) * (3 * D) + h * 64 + vd0 + 2 * D;
  // permuted key label for vr0 (aligned-4 group stays contiguous):
  const int kB0 = ((vr0 >> 5) << 5) | (((vr0 >> 2) & 3) << 3) | (((vr0 >> 4) & 1) << 2);

  f32x4 Oacc[4] = {};
  float li = 0.f;
  const float SC = 0.125f * 1.44269504089f;  // DH^-0.5 * log2(e)

  bf16x8 kA0, kA1, kB0r, kB1r;
  bf16x4 vA[4], vB[4];

  auto loadT = [&](int tile, bf16x8& k0, bf16x8& k1, bf16x4* vp) {
    const size_t ko = kbase + (size_t)tile * 64 * (3 * D);
    const size_t vo = vbase + (size_t)tile * 64 * (3 * D);
    k0 = *(const bf16x8*)&qkv[ko];
    k1 = *(const bf16x8*)&qkv[ko + 8];
#pragma unroll
    for (int i = 0; i < 4; i++)
      vp[i] = *(const bf16x4*)&qkv[vo + (size_t)i * (3 * D)];
  };
  auto writeT = [&](int buf, const bf16x8& k0, const bf16x8& k1, const bf16x4* vp) {
    *(bf16x8*)&Ks[buf][srow][sc0] = k0;
    *(bf16x8*)&Ks[buf][srow][sc0 + 8] = k1;
#pragma unroll
    for (int j = 0; j < 4; j++) {
      int d = vd0 + j;
      bf16x4 w;
      w[0] = vp[0][j]; w[1] = vp[1][j]; w[2] = vp[2][j]; w[3] = vp[3][j];
      *(bf16x4*)&VTs[buf][d][kB0 ^ ((d & 7) * 8)] = w;
    }
  };
  auto computeT = [&](int buf) {
    // S^T = K Q^T : C rows = keys, cols = q
    f32x4 sac[4];
#pragma unroll
    for (int nt = 0; nt < 4; nt++) {
      bf16x8 ak0 = *(const bf16x8*)&Ks[buf][nt * 16 + l16][quad * 8];
      bf16x8 ak1 = *(const bf16x8*)&Ks[buf][nt * 16 + l16][32 + quad * 8];
      f32x4 z = {};
      z = __builtin_amdgcn_mfma_f32_16x16x32_bf16(ak0, bq0, z, 0, 0, 0);
      sac[nt] = __builtin_amdgcn_mfma_f32_16x16x32_bf16(ak1, bq1, z, 0, 0, 0);
    }
    // exp (max-free) + pack straight into PV B-frags
    bf16x8 pv0, pv1;
    float ls = 0.f;
#pragma unroll
    for (int r = 0; r < 4; r++) {
      float e0 = exp2f(sac[0][r] * SC);
      float e1 = exp2f(sac[1][r] * SC);
      float e2 = exp2f(sac[2][r] * SC);
      float e3 = exp2f(sac[3][r] * SC);
      ls += (e0 + e1) + (e2 + e3);
      pv0[r] = (bf16)e0; pv0[4 + r] = (bf16)e1;
      pv1[r] = (bf16)e2; pv1[4 + r] = (bf16)e3;
    }
    li += ls;
    // O^T += V^T P^T
    const int vsw = (l16 & 7) * 8;
#pragma unroll
    for (int dt = 0; dt < 4; dt++) {
      bf16x8 av0 = *(const bf16x8*)&VTs[buf][dt * 16 + l16][(quad * 8) ^ vsw];
      bf16x8 av1 = *(const bf16x8*)&VTs[buf][dt * 16 + l16][(32 + quad * 8) ^ vsw];
      Oacc[dt] = __builtin_amdgcn_mfma_f32_16x16x32_bf16(av0, pv0, Oacc[dt], 0, 0, 0);
      Oacc[dt] = __builtin_amdgcn_mfma_f32_16x16x32_bf16(av1, pv1, Oacc[dt], 0, 0, 0);
    }
  };

  // prologue: tile0 -> set A -> LDS buf0; tile1 -> set B (in flight)
  loadT(0, kA0, kA1, vA);
  if (n > 1) loadT(1, kB0r, kB1r, vB);
  writeT(0, kA0, kA1, vA);

  for (int tt = 0; tt < n; tt += 2) {
    lds_barrier();  // buf0 writes visible; prior reads of buf1 done (lgkm only)
    if (tt + 1 < n) writeT(1, kB0r, kB1r, vB);
    if (tt + 2 < n) loadT(tt + 2, kA0, kA1, vA);
    computeT(0);
    if (tt + 1 >= n) break;
    lds_barrier();  // buf1 writes visible; prior reads of buf0 done
    if (tt + 2 < n) writeT(0, kA0, kA1, vA);
    if (tt + 3 < n) loadT(tt + 3, kB0r, kB1r, vB);
    computeT(1);
  }

  // reduce li across quads (q = l16 fixed per lane across all its values)
  li += __shfl_xor(li, 16);
  li += __shfl_xor(li, 32);
  const float inv = 1.f / li;

  // epilogue: transpose O^T via LDS (reuse Ks[0]) for coalesced stores
  __syncthreads();  // all waves done reading Ks/VTs
  bf16(*Osh)[72] = (bf16(*)[72])Ks[0];
  const int orow = wave * 16 + l16;
#pragma unroll
  for (int dt = 0; dt < 4; dt++) {
    int dg = dt * 16 + quad * 4;
    bf16x4 w;
#pragma unroll
    for (int r = 0; r < 4; r++) w[r] = (bf16)(Oacc[dt][r] * inv);
    *(bf16x4*)&Osh[orow][dg ^ ((l16 & 7) * 8)] = w;  // wave-private row
  }
  // read back own row (within-wave: lgkm ordering only, no barrier)
  const int osw = (l16 & 7) * 8;
  bf16x8 o0 = *(const bf16x8*)&Osh[orow][(quad * 16) ^ osw];
  bf16x8 o1 = *(const bf16x8*)&Osh[orow][(quad * 16 + 8) ^ osw];
  const size_t obase = (size_t)(tok0 + orow) * D + h * 64 + quad * 16;
  *(bf16x8*)&attn[obase] = o0;
  *(bf16x8*)&attn[obase + 8] = o1;
}

// ---------------------------------------------------------------- launch
extern "C" void kernel_launch(void* const* d_in, const int* in_sizes, int n_in,
                              void* d_out, int out_size, void* d_ws,
                              size_t ws_size, hipStream_t stream) {
  const float* x       = (const float*)d_in[0];
  const float* norm1_w = (const float*)d_in[1];
  const float* norm1_b = (const float*)d_in[2];
  const float* qkv_w   = (const float*)d_in[3];
  const float* qkv_b   = (const float*)d_in[4];
  const float* proj_w  = (const float*)d_in[5];
  const float* proj_b  = (const float*)d_in[6];
  const float* ls1     = (const float*)d_in[7];
  const float* norm2_w = (const float*)d_in[8];
  const float* norm2_b = (const float*)d_in[9];
  const float* fc1_w   = (const float*)d_in[10];
  const float* fc1_b   = (const float*)d_in[11];
  const float* fc2_w   = (const float*)d_in[12];
  const float* fc2_b   = (const float*)d_in[13];
  const float* ls2     = (const float*)d_in[14];
  const int*   cu      = (const int*)d_in[15];
  float* out = (float*)d_out;

  char* ws = (char*)d_ws;
  size_t off = 0;
  auto alloc = [&](size_t bytes) {
    void* p = ws + off;
    off += (bytes + 255) & ~(size_t)255;
    return p;
  };
  bf16* w_qkv  = (bf16*)alloc((size_t)3 * D * D * 2);
  bf16* w_proj = (bf16*)alloc((size_t)D * D * 2);
  bf16* w_fc1  = (bf16*)alloc((size_t)DFF * D * 2);
  bf16* w_fc2  = (bf16*)alloc((size_t)D * DFF * 2);
  bf16* xn     = (bf16*)alloc((size_t)TOTAL * D * 2);      // reused as xn2
  bf16* qkv    = (bf16*)alloc((size_t)TOTAL * 3 * D * 2);  // h aliases qkv+attnb
  bf16* attnb  = (bf16*)alloc((size_t)TOTAL * D * 2);
  float* x1    = (float*)alloc((size_t)TOTAL * D * 4);
  bf16* hbuf   = qkv;  // [TOTAL][DFF] overlaps dead qkv(3D)+attnb(D) exactly

  // one conversion kernel: dst regions are exactly contiguous from w_qkv
  {
    int nA   = 3 * D * D / 4;
    int nAB  = nA + D * D / 4;
    int nABC = nAB + DFF * D / 4;
    int nTot = nABC + D * DFF / 4;
    cvt_all_kernel<<<(nTot + 255) / 256, 256, 0, stream>>>(
        qkv_w, proj_w, fc1_w, fc2_w, w_qkv, nA, nAB, nABC, nTot);
  }

  ln_kernel<<<TOTAL, 256, 0, stream>>>(x, norm1_w, norm1_b, xn);

  constexpr int GY = TOTAL / 128;        // 36 M-tiles
  constexpr int GYP = ((GY + 7) / 8) * 8;  // padded to 40

  // QKV: N=2304, GX=18
  gemm_kernel<0, 128, 64, 18, GY><<<18 * GYP, 256, 0, stream>>>(
      xn, w_qkv, qkv_b, nullptr, nullptr, qkv, nullptr, 3 * D, D);

  dim3 ga(HEADS, TOTAL / 64);  // h fastest: heavy q-tiles spread across CUs
  attn_kernel<<<ga, 256, 0, stream>>>(qkv, cu, attnb);

  // proj: N=768, TN=64, GX=12
  gemm_kernel<1, 64, 64, 12, GY><<<12 * GYP, 256, 0, stream>>>(
      attnb, w_proj, proj_b, x, ls1, nullptr, x1, D, D);

  ln_kernel<<<TOTAL, 256, 0, stream>>>(x1, norm2_w, norm2_b, xn);

  // FC1: N=3072, GX=24
  gemm_kernel<2, 128, 64, 24, GY><<<24 * GYP, 256, 0, stream>>>(
      xn, w_fc1, fc1_b, nullptr, nullptr, hbuf, nullptr, DFF, D);

  // FC2: N=768, TN=64, K=3072, GX=12
  gemm_kernel<1, 64, 64, 12, GY><<<12 * GYP, 256, 0, stream>>>(
      hbuf, w_fc2, fc2_b, x1, ls2, nullptr, out, D, DFF);
}